// Round 9
// baseline (502.409 us; speedup 1.0000x reference)
//
#include <hip/hip_runtime.h>
#include <hip/hip_bf16.h>

#define NN 50000
#define EE 800000
#define IN_F 128
#define HC 64
#define NEG_SLOPE 0.2f
#define BN_EPS 1e-5f

#define BSH 7                 // bucket = dst >> 7 (128 nodes per bucket)
#define BMASK 127
#define NBKT 391              // 49999>>7 = 390
#define NBLKS 200             // sort blocks
#define EPB2 (EE / NBLKS)     // 4000 edges per sort block
#define TOTH (NBKT * NBLKS)   // 78200

typedef __attribute__((ext_vector_type(8))) short short8;
typedef __attribute__((ext_vector_type(4))) float f32x4;

__device__ __forceinline__ ushort f2bf(float f) {
  uint u = __float_as_uint(f);
  uint r = u + 0x7FFF + ((u >> 16) & 1);   // RNE
  return (ushort)(r >> 16);
}
__device__ __forceinline__ float bf2f(ushort u) {
  return __uint_as_float(((uint)u) << 16);
}

// ---------------- Kernel 1: MFMA bf16 GEMM: h=x@W (bf16 out), res=x@Wres (f32), al_s, al_d --
__global__ __launch_bounds__(256) void gemm_mfma_kernel(
    const float* __restrict__ x, const float* __restrict__ W, const float* __restrict__ Wres,
    const float* __restrict__ a_src, const float* __restrict__ a_dst,
    ushort* __restrict__ h, float* __restrict__ res,
    float* __restrict__ al_s, float* __restrict__ al_d) {
  __shared__ ushort bs[128 * 128];   // [col][k] bf16, swizzled: byte ^= (col&7)<<4
  __shared__ ushort xs[64 * 128];    // [row][k] bf16, swizzled: byte ^= (row&7)<<4

  const int tid = threadIdx.x;
  const int r0 = blockIdx.x * 64;

  {
    const int c4 = (tid & 31) * 4;
    const int kb = (tid >> 5) * 16;
    const float* src0 = (c4 < HC) ? (W + c4) : (Wres + (c4 - HC));
    char* base = (char*)bs;
#pragma unroll
    for (int j = 0; j < 8; ++j) {
      int k0 = kb + j * 2;
      float4 fa = *(const float4*)(src0 + (size_t)k0 * HC);
      float4 fb = *(const float4*)(src0 + (size_t)(k0 + 1) * HC);
      uint p0 = (uint)f2bf(fa.x) | ((uint)f2bf(fb.x) << 16);
      uint p1 = (uint)f2bf(fa.y) | ((uint)f2bf(fb.y) << 16);
      uint p2 = (uint)f2bf(fa.z) | ((uint)f2bf(fb.z) << 16);
      uint p3 = (uint)f2bf(fa.w) | ((uint)f2bf(fb.w) << 16);
      *(uint*)(base + (((c4 + 0) * 256 + k0 * 2) ^ (((c4 + 0) & 7) << 4))) = p0;
      *(uint*)(base + (((c4 + 1) * 256 + k0 * 2) ^ (((c4 + 1) & 7) << 4))) = p1;
      *(uint*)(base + (((c4 + 2) * 256 + k0 * 2) ^ (((c4 + 2) & 7) << 4))) = p2;
      *(uint*)(base + (((c4 + 3) * 256 + k0 * 2) ^ (((c4 + 3) & 7) << 4))) = p3;
    }
  }
  {
    char* base = (char*)xs;
#pragma unroll
    for (int i = 0; i < 8; ++i) {
      int f4 = i * 256 + tid;
      int row = f4 >> 5;
      int kq = (f4 & 31) * 4;
      int gr = r0 + row;
      float4 v = make_float4(0.f, 0.f, 0.f, 0.f);
      if (gr < NN) v = *(const float4*)(x + (size_t)gr * IN_F + kq);
      uint lo = (uint)f2bf(v.x) | ((uint)f2bf(v.y) << 16);
      uint hi = (uint)f2bf(v.z) | ((uint)f2bf(v.w) << 16);
      uint off = (uint)((row * 256 + kq * 2) ^ ((row & 7) << 4));
      *(uint2*)(base + off) = make_uint2(lo, hi);
    }
  }
  __syncthreads();

  const int w = tid >> 6;
  const int l = tid & 63;
  const int lr = l & 15;
  const int lk = (l >> 4) * 8;

  f32x4 acc[8];
#pragma unroll
  for (int i = 0; i < 8; ++i) acc[i] = (f32x4){0.f, 0.f, 0.f, 0.f};

  const char* xb = (const char*)xs;
  const char* bb = (const char*)bs;
  const int arow = w * 16 + lr;
#pragma unroll
  for (int ks = 0; ks < 4; ++ks) {
    const int kbase = ks * 32 + lk;
    short8 af = *(const short8*)(xb + ((arow * 256 + kbase * 2) ^ ((arow & 7) << 4)));
#pragma unroll
    for (int ct = 0; ct < 8; ++ct) {
      const int c = ct * 16 + lr;
      short8 bfr = *(const short8*)(bb + ((c * 256 + kbase * 2) ^ ((c & 7) << 4)));
      acc[ct] = __builtin_amdgcn_mfma_f32_16x16x32_bf16(af, bfr, acc[ct], 0, 0, 0);
    }
  }

  const int rb = r0 + w * 16;
#pragma unroll
  for (int ct = 0; ct < 8; ++ct) {
#pragma unroll
    for (int r = 0; r < 4; ++r) {
      int gr = rb + (l >> 4) * 4 + r;
      if (gr < NN) {
        if (ct < 4) h[(size_t)gr * HC + ct * 16 + lr] = f2bf(acc[ct][r]);
        else        res[(size_t)gr * HC + (ct - 4) * 16 + lr] = acc[ct][r];
      }
    }
  }

  float myS[4] = {0.f, 0.f, 0.f, 0.f};
  float myD[4] = {0.f, 0.f, 0.f, 0.f};
#pragma unroll
  for (int ct = 0; ct < 4; ++ct) {
    float asv = a_src[ct * 16 + lr];
    float adv = a_dst[ct * 16 + lr];
#pragma unroll
    for (int r = 0; r < 4; ++r) {
      float ps = acc[ct][r] * asv;
      float pd = acc[ct][r] * adv;
      ps += __shfl_xor(ps, 1); ps += __shfl_xor(ps, 2); ps += __shfl_xor(ps, 4); ps += __shfl_xor(ps, 8);
      pd += __shfl_xor(pd, 1); pd += __shfl_xor(pd, 2); pd += __shfl_xor(pd, 4); pd += __shfl_xor(pd, 8);
      if (lr == ct) { myS[r] = ps; myD[r] = pd; }
    }
  }
  if (lr < 4) {
#pragma unroll
    for (int r = 0; r < 4; ++r) {
      int gr = rb + (l >> 4) * 4 + r;
      if (gr < NN) {
        al_s[gr * 4 + lr] = myS[r];
        al_d[gr * 4 + lr] = myD[r];
      }
    }
  }
}

// ---------------- Kernel 2: per-block bucket histogram ----------------
__global__ __launch_bounds__(256) void histB_kernel(const int* __restrict__ dst,
                                                    int* __restrict__ histmat) {
  __shared__ int lh[NBKT];
  const int tid = threadIdx.x;
  for (int i = tid; i < NBKT; i += 256) lh[i] = 0;
  __syncthreads();
  const int ebase = blockIdx.x * EPB2;
  for (int off = tid; off < EPB2; off += 256)
    atomicAdd(&lh[dst[ebase + off] >> BSH], 1);
  __syncthreads();
  for (int i = tid; i < NBKT; i += 256) histmat[i * NBLKS + blockIdx.x] = lh[i];
}

// ---------------- Kernel 3: per-bucket absolute bases (391 independent blocks) ----------
// Block b: prefix = sum of all earlier buckets' rows (raw histmat, read-only), then
// exclusive-scan own row -> histabs (absolute placement base per (bucket, sort-block)).
__global__ __launch_bounds__(256) void scanB_kernel(const int* __restrict__ histmat,
                                                    int* __restrict__ histabs,
                                                    int* __restrict__ bucket_base) {
  const int b = blockIdx.x;
  const int t = threadIdx.x;
  const int lane = t & 63;
  const int wv = t >> 6;
  // cooperative sum of histmat[0 .. b*NBLKS)
  int part = 0;
  for (int i = t; i < b * NBLKS; i += 256) part += histmat[i];
#pragma unroll
  for (int off = 1; off < 64; off <<= 1) part += __shfl_xor(part, off);
  __shared__ int ws1[4];
  if (lane == 0) ws1[wv] = part;
  __syncthreads();
  const int prefix = ws1[0] + ws1[1] + ws1[2] + ws1[3];
  // exclusive scan of own row
  int v = (t < NBLKS) ? histmat[b * NBLKS + t] : 0;
  int incl = v;
#pragma unroll
  for (int off = 1; off < 64; off <<= 1) {
    int tt = __shfl_up(incl, off);
    if (lane >= off) incl += tt;
  }
  __shared__ int ws2[4];
  if (lane == 63) ws2[wv] = incl;
  __syncthreads();
  int woff = 0;
  for (int w = 0; w < wv; ++w) woff += ws2[w];
  if (t < NBLKS) histabs[b * NBLKS + t] = prefix + woff + incl - v;
  if (t == 0) bucket_base[b] = prefix;
  if (b == 0 && t == 0) bucket_base[NBKT] = EE;
}

// ---------------- Kernel 4: place edges into bucket-sorted pairs (+ zero BN sums) ------
__global__ __launch_bounds__(256) void placeB_kernel(const int* __restrict__ src,
                                                     const int* __restrict__ dst,
                                                     const int* __restrict__ histabs,
                                                     uint* __restrict__ pairs,
                                                     float* __restrict__ sums) {
  __shared__ int cur[NBKT];
  const int tid = threadIdx.x;
  if (blockIdx.x == 0 && tid < 128) sums[tid] = 0.f;   // init BN accumulators (used later)
  for (int i = tid; i < NBKT; i += 256) cur[i] = histabs[i * NBLKS + blockIdx.x];
  __syncthreads();
  const int ebase = blockIdx.x * EPB2;
  for (int off = tid; off < EPB2; off += 256) {
    const int e = ebase + off;
    const int d = dst[e];
    const uint val = ((uint)(d & BMASK) << 16) | (uint)src[e];
    int p = atomicAdd(&cur[d >> BSH], 1);
    pairs[p] = val;
  }
}

// ---------------- Kernel 5: fused attention aggregate (one block per 128-node bucket) --
// LDS accumulators; phase A computes 16 edges' softmax numerators vectorized
// (lane = edge*4+head), phase B does one h-line gather + conflict-free ds_add per edge.
// Self-loops folded into the accumulator init. No CSR, no col/mvals materialization.
__global__ __launch_bounds__(512) void nodeB_kernel(
    const ushort* __restrict__ h, const float* __restrict__ al_s, const float* __restrict__ al_d,
    const int* __restrict__ bucket_base, const uint* __restrict__ pairs,
    float* __restrict__ out_pre) {
  __shared__ float acc[128 * 64];   // 32KB
  __shared__ float den[128 * 4];
  __shared__ float adl[128 * 4];
  __shared__ float m_scr[8 * 64];
  __shared__ int   s_scr[8 * 16];
  __shared__ int   d_scr[8 * 16];

  const int b = blockIdx.x;
  const int t = threadIdx.x;
  const int lane = t & 63;
  const int wv = t >> 6;

  // stage al_d + self-loop numerator (den init)
  {
    const int n = t >> 2, hd = t & 3;
    const int node = (b << BSH) + n;
    float als = 0.f, ald = 0.f;
    if (node < NN) { als = al_s[(size_t)node * 4 + hd]; ald = al_d[(size_t)node * 4 + hd]; }
    adl[t] = ald;
    float e0 = als + ald;
    e0 = e0 > 0.f ? e0 : NEG_SLOPE * e0;
    den[t] = (node < NN) ? __expf(e0) : 1.f;
  }
  __syncthreads();
  // acc init = m0 * h[self]
#pragma unroll
  for (int i = 0; i < 16; ++i) {
    const int idx = t + i * 512;
    const int n = idx >> 6, ch = idx & 63;
    const int node = (b << BSH) + n;
    float hv = (node < NN) ? bf2f(h[(size_t)node * HC + ch]) : 0.f;
    acc[idx] = den[n * 4 + (ch >> 4)] * hv;
  }
  __syncthreads();

  const int lo = bucket_base[b];
  const int hi = bucket_base[b + 1];
  const int cnt = hi - lo;
  const int seg = (cnt + 7) >> 3;          // edges per wave (8 waves)
  const int wlo = lo + wv * seg;
  const int whi = (wlo + seg < hi) ? (wlo + seg) : hi;

  for (int g = wlo; g < whi; g += 16) {
    // phase A: 16 edges x 4 heads = 64 lanes compute numerators
    const int e = g + (lane >> 2);
    const bool valid = e < whi;
    const uint u = valid ? pairs[e] : 0u;
    const int s = (int)(u & 0xFFFFu);
    const int dl = (int)((u >> 16) & BMASK);
    const int hd = lane & 3;
    float als = valid ? al_s[(size_t)s * 4 + hd] : 0.f;
    float ee = als + adl[dl * 4 + hd];
    ee = ee > 0.f ? ee : NEG_SLOPE * ee;
    const float m = valid ? __expf(ee) : 0.f;
    m_scr[wv * 64 + lane] = m;             // index == e_loc*4+head == lane
    atomicAdd(&den[dl * 4 + hd], m);
    if (hd == 0) { s_scr[wv * 16 + (lane >> 2)] = s; d_scr[wv * 16 + (lane >> 2)] = dl; }
    // phase B: per edge, gather h line + LDS accumulate (same wave, no barrier needed)
#pragma unroll
    for (int el = 0; el < 16; ++el) {
      const int ss = s_scr[wv * 16 + el];
      const int dd = d_scr[wv * 16 + el];
      const float mm = m_scr[wv * 64 + el * 4 + (lane >> 4)];
      const float hv = bf2f(h[(size_t)ss * HC + lane]);
      atomicAdd(&acc[dd * 64 + lane], mm * hv);
    }
  }
  __syncthreads();
#pragma unroll
  for (int i = 0; i < 16; ++i) {
    const int idx = t + i * 512;
    const int n = idx >> 6, ch = idx & 63;
    const int node = (b << BSH) + n;
    if (node < NN)
      out_pre[(size_t)node * HC + ch] = acc[idx] / den[n * 4 + (ch >> 4)];
  }
}

// ---------------- Kernel 6: BN statistics ----------------
__global__ __launch_bounds__(256) void stats_kernel(const float* __restrict__ out_pre,
                                                    float* __restrict__ sums) {
  const int c = threadIdx.x & 63;
  const int rg = threadIdx.x >> 6;
  float s = 0.f, s2 = 0.f;
  for (int r = blockIdx.x * 4 + rg; r < NN; r += gridDim.x * 4) {
    float v = out_pre[(size_t)r * HC + c];
    s += v;
    s2 = fmaf(v, v, s2);
  }
  __shared__ float lds[512];
  lds[threadIdx.x] = s;
  lds[256 + threadIdx.x] = s2;
  __syncthreads();
  if (threadIdx.x < 64) {
    float ts = lds[c] + lds[64 + c] + lds[128 + c] + lds[192 + c];
    float t2 = lds[256 + c] + lds[256 + 64 + c] + lds[256 + 128 + c] + lds[256 + 192 + c];
    atomicAdd(&sums[c], ts);
    atomicAdd(&sums[64 + c], t2);
  }
}

// ---------------- Kernel 7: BN + ELU + residual ----------------
__global__ __launch_bounds__(256) void final_kernel(
    const float* __restrict__ out_pre, const float* __restrict__ res,
    const float* __restrict__ sums, const float* __restrict__ gamma,
    const float* __restrict__ beta, float* __restrict__ out) {
  const int i = blockIdx.x * 256 + threadIdx.x;
  const int c = i & 63;
  const float inv_n = 1.0f / (float)NN;
  float mu = sums[c] * inv_n;
  float var = sums[64 + c] * inv_n - mu * mu;
  float rinv = rsqrtf(var + BN_EPS);
  float v = (out_pre[i] - mu) * rinv * gamma[c] + beta[c];
  v = v > 0.f ? v : (__expf(v) - 1.0f);
  out[i] = v + res[i];
}

extern "C" void kernel_launch(void* const* d_in, const int* in_sizes, int n_in,
                              void* d_out, int out_size, void* d_ws, size_t ws_size,
                              hipStream_t stream) {
  const float* x     = (const float*)d_in[0];
  const int*   ei    = (const int*)d_in[1];     // [2,E]: src = ei, dst = ei+E
  const float* W     = (const float*)d_in[2];
  const float* a_src = (const float*)d_in[3];
  const float* a_dst = (const float*)d_in[4];
  // d_in[5] = bias: cancels exactly through BatchNorm mean-subtraction -> unused
  const float* gamma = (const float*)d_in[6];
  const float* beta  = (const float*)d_in[7];
  const float* Wres  = (const float*)d_in[8];
  float* out = (float*)d_out;

  char* ws = (char*)d_ws;
  ushort* h        = (ushort*)ws; ws += (size_t)NN * HC * 2;   // bf16 h
  float* resb      = (float*)ws;  ws += (size_t)NN * HC * 4;
  float* out_pre   = (float*)ws;  ws += (size_t)NN * HC * 4;
  float* al_s      = (float*)ws;  ws += (size_t)NN * 4 * 4;
  float* al_d      = (float*)ws;  ws += (size_t)NN * 4 * 4;
  float* sums      = (float*)ws;  ws += 128 * 4;               // [0:64]=sum, [64:128]=sumsq
  int*   histmat   = (int*)ws;    ws += (size_t)TOTH * 4;      // [bucket][block] raw
  int*   histabs   = (int*)ws;    ws += (size_t)TOTH * 4;      // [bucket][block] absolute
  int*   bucket_base = (int*)ws;  ws += (NBKT + 1) * 4;
  uint*  pairs     = (uint*)ws;   ws += (size_t)EE * 4;

  gemm_mfma_kernel<<<(NN + 63) / 64, 256, 0, stream>>>(x, W, Wres, a_src, a_dst,
                                                       h, resb, al_s, al_d);
  histB_kernel<<<NBLKS, 256, 0, stream>>>(ei + EE, histmat);
  scanB_kernel<<<NBKT, 256, 0, stream>>>(histmat, histabs, bucket_base);
  placeB_kernel<<<NBLKS, 256, 0, stream>>>(ei, ei + EE, histabs, pairs, sums);
  nodeB_kernel<<<NBKT, 512, 0, stream>>>(h, al_s, al_d, bucket_base, pairs, out_pre);
  stats_kernel<<<256, 256, 0, stream>>>(out_pre, sums);
  final_kernel<<<NN * HC / 256, 256, 0, stream>>>(out_pre, resb, sums, gamma, beta, out);
}

// Round 10
// 154.108 us; speedup vs baseline: 3.2601x; 3.2601x over previous
//
#include <hip/hip_runtime.h>
#include <hip/hip_bf16.h>

#define NN 50000
#define EE 800000
#define IN_F 128
#define HC 64
#define NEG_SLOPE 0.2f
#define BN_EPS 1e-5f
#define SCAN_NB ((NN + 1023) / 1024)   // 49 blocks of 1024 elements

#define NBKT 196          // buckets of 256 nodes: dst>>8 (max 49999>>8 = 195)
#define NBLKS 200         // sort blocks
#define EPB2 (EE / NBLKS) // 4000 edges per sort block
#define TOTH (NBKT * NBLKS)  // 39200
#define NZERO (128 + NN)  // ints to zero (sums + counts, adjacent)

typedef __attribute__((ext_vector_type(8))) short short8;
typedef __attribute__((ext_vector_type(4))) float f32x4;

__device__ __forceinline__ ushort f2bf(float f) {
  uint u = __float_as_uint(f);
  uint r = u + 0x7FFF + ((u >> 16) & 1);   // RNE
  return (ushort)(r >> 16);
}
__device__ __forceinline__ float bf2f(ushort u) {
  return __uint_as_float(((uint)u) << 16);
}

// ---------------- Kernel 0: zero sums+counts ----------------
__global__ __launch_bounds__(256) void zero_kernel(int4* __restrict__ p) {
  int i = blockIdx.x * 256 + threadIdx.x;
  if (i < NZERO / 4) p[i] = make_int4(0, 0, 0, 0);
}

// ---------------- Kernel 1: MFMA bf16 GEMM: h=x@W (bf16 out), res=x@Wres (f32), al_s, al_d --
__global__ __launch_bounds__(256) void gemm_mfma_kernel(
    const float* __restrict__ x, const float* __restrict__ W, const float* __restrict__ Wres,
    const float* __restrict__ a_src, const float* __restrict__ a_dst,
    ushort* __restrict__ h, float* __restrict__ res,
    float* __restrict__ al_s, float* __restrict__ al_d) {
  __shared__ ushort bs[128 * 128];   // [col][k] bf16, swizzled: byte ^= (col&7)<<4
  __shared__ ushort xs[64 * 128];    // [row][k] bf16, swizzled: byte ^= (row&7)<<4

  const int tid = threadIdx.x;
  const int r0 = blockIdx.x * 64;

  {
    const int c4 = (tid & 31) * 4;
    const int kb = (tid >> 5) * 16;
    const float* src0 = (c4 < HC) ? (W + c4) : (Wres + (c4 - HC));
    char* base = (char*)bs;
#pragma unroll
    for (int j = 0; j < 8; ++j) {
      int k0 = kb + j * 2;
      float4 fa = *(const float4*)(src0 + (size_t)k0 * HC);
      float4 fb = *(const float4*)(src0 + (size_t)(k0 + 1) * HC);
      uint p0 = (uint)f2bf(fa.x) | ((uint)f2bf(fb.x) << 16);
      uint p1 = (uint)f2bf(fa.y) | ((uint)f2bf(fb.y) << 16);
      uint p2 = (uint)f2bf(fa.z) | ((uint)f2bf(fb.z) << 16);
      uint p3 = (uint)f2bf(fa.w) | ((uint)f2bf(fb.w) << 16);
      *(uint*)(base + (((c4 + 0) * 256 + k0 * 2) ^ (((c4 + 0) & 7) << 4))) = p0;
      *(uint*)(base + (((c4 + 1) * 256 + k0 * 2) ^ (((c4 + 1) & 7) << 4))) = p1;
      *(uint*)(base + (((c4 + 2) * 256 + k0 * 2) ^ (((c4 + 2) & 7) << 4))) = p2;
      *(uint*)(base + (((c4 + 3) * 256 + k0 * 2) ^ (((c4 + 3) & 7) << 4))) = p3;
    }
  }
  {
    char* base = (char*)xs;
#pragma unroll
    for (int i = 0; i < 8; ++i) {
      int f4 = i * 256 + tid;
      int row = f4 >> 5;
      int kq = (f4 & 31) * 4;
      int gr = r0 + row;
      float4 v = make_float4(0.f, 0.f, 0.f, 0.f);
      if (gr < NN) v = *(const float4*)(x + (size_t)gr * IN_F + kq);
      uint lo = (uint)f2bf(v.x) | ((uint)f2bf(v.y) << 16);
      uint hi = (uint)f2bf(v.z) | ((uint)f2bf(v.w) << 16);
      uint off = (uint)((row * 256 + kq * 2) ^ ((row & 7) << 4));
      *(uint2*)(base + off) = make_uint2(lo, hi);
    }
  }
  __syncthreads();

  const int w = tid >> 6;
  const int l = tid & 63;
  const int lr = l & 15;
  const int lk = (l >> 4) * 8;

  f32x4 acc[8];
#pragma unroll
  for (int i = 0; i < 8; ++i) acc[i] = (f32x4){0.f, 0.f, 0.f, 0.f};

  const char* xb = (const char*)xs;
  const char* bb = (const char*)bs;
  const int arow = w * 16 + lr;
#pragma unroll
  for (int ks = 0; ks < 4; ++ks) {
    const int kbase = ks * 32 + lk;
    short8 af = *(const short8*)(xb + ((arow * 256 + kbase * 2) ^ ((arow & 7) << 4)));
#pragma unroll
    for (int ct = 0; ct < 8; ++ct) {
      const int c = ct * 16 + lr;
      short8 bfr = *(const short8*)(bb + ((c * 256 + kbase * 2) ^ ((c & 7) << 4)));
      acc[ct] = __builtin_amdgcn_mfma_f32_16x16x32_bf16(af, bfr, acc[ct], 0, 0, 0);
    }
  }

  const int rb = r0 + w * 16;
#pragma unroll
  for (int ct = 0; ct < 8; ++ct) {
#pragma unroll
    for (int r = 0; r < 4; ++r) {
      int gr = rb + (l >> 4) * 4 + r;
      if (gr < NN) {
        if (ct < 4) h[(size_t)gr * HC + ct * 16 + lr] = f2bf(acc[ct][r]);
        else        res[(size_t)gr * HC + (ct - 4) * 16 + lr] = acc[ct][r];
      }
    }
  }

  float myS[4] = {0.f, 0.f, 0.f, 0.f};
  float myD[4] = {0.f, 0.f, 0.f, 0.f};
#pragma unroll
  for (int ct = 0; ct < 4; ++ct) {
    float asv = a_src[ct * 16 + lr];
    float adv = a_dst[ct * 16 + lr];
#pragma unroll
    for (int r = 0; r < 4; ++r) {
      float ps = acc[ct][r] * asv;
      float pd = acc[ct][r] * adv;
      ps += __shfl_xor(ps, 1); ps += __shfl_xor(ps, 2); ps += __shfl_xor(ps, 4); ps += __shfl_xor(ps, 8);
      pd += __shfl_xor(pd, 1); pd += __shfl_xor(pd, 2); pd += __shfl_xor(pd, 4); pd += __shfl_xor(pd, 8);
      if (lr == ct) { myS[r] = ps; myD[r] = pd; }
    }
  }
  if (lr < 4) {
#pragma unroll
    for (int r = 0; r < 4; ++r) {
      int gr = rb + (l >> 4) * 4 + r;
      if (gr < NN) {
        al_s[gr * 4 + lr] = myS[r];
        al_d[gr * 4 + lr] = myD[r];
      }
    }
  }
}

// ---------------- Kernel 2: per-block bucket histogram + per-node counts ----------------
__global__ __launch_bounds__(256) void histB_kernel(const int* __restrict__ dst,
                                                    int* __restrict__ counts,
                                                    int* __restrict__ histmat) {
  __shared__ int lh[NBKT];
  const int tid = threadIdx.x;
  for (int i = tid; i < NBKT; i += 256) lh[i] = 0;
  __syncthreads();
  const int ebase = blockIdx.x * EPB2;
  for (int off = tid; off < EPB2; off += 256) {
    int d = dst[ebase + off];
    atomicAdd(&lh[d >> 8], 1);
    atomicAdd(&counts[d], 1);         // per-node degree (for row_ptr)
  }
  __syncthreads();
  for (int i = tid; i < NBKT; i += 256) histmat[i * NBLKS + blockIdx.x] = lh[i];
}

// ---------------- Kernel 3a: per-block scan of counts -> row_ptr (+ blk_sums) ----------
__global__ __launch_bounds__(256) void scan1_kernel(const int* __restrict__ counts,
                                                    int* __restrict__ row_ptr,
                                                    int* __restrict__ blk_sums) {
  const int tid = threadIdx.x;
  const int base = blockIdx.x * 1024 + tid * 4;
  int4 v = make_int4(0, 0, 0, 0);
  if (base + 3 < NN) {
    v = *(const int4*)&counts[base];
  } else {
    if (base + 0 < NN) v.x = counts[base + 0];
    if (base + 1 < NN) v.y = counts[base + 1];
    if (base + 2 < NN) v.z = counts[base + 2];
    if (base + 3 < NN) v.w = counts[base + 3];
  }
  const int s = v.x + v.y + v.z + v.w;
  const int lane = tid & 63;
  const int wave = tid >> 6;
  int incl = s;
#pragma unroll
  for (int off = 1; off < 64; off <<= 1) {
    int t = __shfl_up(incl, off);
    if (lane >= off) incl += t;
  }
  __shared__ int wsum[4];
  if (lane == 63) wsum[wave] = incl;
  __syncthreads();
  int woff = 0;
  for (int w = 0; w < wave; ++w) woff += wsum[w];
  const int excl = woff + incl - s;
  int4 o;
  o.x = excl;
  o.y = o.x + v.x;
  o.z = o.y + v.y;
  o.w = o.z + v.z;
  if (base + 3 < NN) {
    *(int4*)&row_ptr[base] = o;
  } else {
    if (base + 0 < NN) row_ptr[base + 0] = o.x;
    if (base + 1 < NN) row_ptr[base + 1] = o.y;
    if (base + 2 < NN) row_ptr[base + 2] = o.z;
    if (base + 3 < NN) row_ptr[base + 3] = o.w;
  }
  if (tid == 255) blk_sums[blockIdx.x] = woff + incl;
}

// ---------------- Kernel 3b: finalize row_ptr (scan2 folded in: 49-elem in-wave scan) --
__global__ __launch_bounds__(256) void scan3_kernel(int* __restrict__ row_ptr,
                                                    const int* __restrict__ blk_sums) {
  __shared__ int off_lds[SCAN_NB + 1];
  const int tid = threadIdx.x;
  if (tid < 64) {
    int v = (tid < SCAN_NB) ? blk_sums[tid] : 0;
    int incl = v;
#pragma unroll
    for (int off = 1; off < 64; off <<= 1) {
      int t = __shfl_up(incl, off);
      if (tid >= off) incl += t;
    }
    if (tid < SCAN_NB) off_lds[tid] = incl - v;   // exclusive offset per 1024-chunk
  }
  __syncthreads();
  int i = blockIdx.x * 256 + tid;
  if (i < NN) row_ptr[i] += off_lds[i >> 10];
  if (i == NN) row_ptr[NN] = EE;                  // grand total is the constant EE
}

// ---------------- Kernel 4: per-bucket scan of histmat rows (196 independent blocks) ----
// bucket_base[b] == row_ptr[b<<8], so seed each row-scan with row_ptr: no global scan.
__global__ __launch_bounds__(256) void scanHB_kernel(int* __restrict__ histmat,
                                                     const int* __restrict__ row_ptr) {
  const int b = blockIdx.x;
  const int tid = threadIdx.x;
  int v = (tid < NBLKS) ? histmat[b * NBLKS + tid] : 0;
  const int lane = tid & 63;
  const int wv = tid >> 6;
  int incl = v;
#pragma unroll
  for (int off = 1; off < 64; off <<= 1) {
    int t = __shfl_up(incl, off);
    if (lane >= off) incl += t;
  }
  __shared__ int wsum[4];
  if (lane == 63) wsum[wv] = incl;
  __syncthreads();
  int woff = 0;
  for (int w = 0; w < wv; ++w) woff += wsum[w];
  if (tid < NBLKS)
    histmat[b * NBLKS + tid] = row_ptr[b << 8] + woff + incl - v;   // exclusive + base
}

// ---------------- Kernel 5: place edges into bucket-sorted pairs ----------------
__global__ __launch_bounds__(256) void placeB_kernel(const int* __restrict__ src,
                                                     const int* __restrict__ dst,
                                                     const int* __restrict__ histmat,
                                                     uint* __restrict__ pairs) {
  __shared__ int cur[NBKT];
  const int tid = threadIdx.x;
  for (int i = tid; i < NBKT; i += 256) cur[i] = histmat[i * NBLKS + blockIdx.x];
  __syncthreads();
  const int ebase = blockIdx.x * EPB2;
  for (int off = tid; off < EPB2; off += 256) {
    const int e = ebase + off;
    const int d = dst[e];
    const uint val = ((uint)(d & 255) << 16) | (uint)src[e];
    int p = atomicAdd(&cur[d >> 8], 1);
    pairs[p] = val;
  }
}

// ---------------- Kernel 6: fine scatter within bucket (LDS cursors) ----------------
__global__ __launch_bounds__(256) void bscatter_kernel(const uint* __restrict__ pairs,
                                                       const int* __restrict__ row_ptr,
                                                       int* __restrict__ col) {
  __shared__ int cur[256];
  const int b = blockIdx.x;
  const int tid = threadIdx.x;
  const int node = (b << 8) + tid;
  cur[tid] = (node < NN) ? row_ptr[node] : 0;
  __syncthreads();
  const int lo = row_ptr[b << 8];
  const int nhi = ((b + 1) << 8) < NN ? ((b + 1) << 8) : NN;
  const int hi = row_ptr[nhi];
  for (int i = lo + tid; i < hi; i += 256) {
    uint v = pairs[i];
    int d = (v >> 16) & 255;
    int p = atomicAdd(&cur[d], 1);
    col[p] = (int)(v & 0xFFFFu);
  }
}

// ---------------- Kernel 7: per-node aggregate (wave per node, 32-bit addressing) ------
__global__ __launch_bounds__(256) void node_kernel(
    const ushort* __restrict__ h, const float* __restrict__ al_s, const float* __restrict__ al_d,
    const int* __restrict__ row_ptr, const int* __restrict__ col,
    float* __restrict__ out_pre) {
  const int node = blockIdx.x * 4 + (threadIdx.x >> 6);
  const uint lane = threadIdx.x & 63;
  const uint head = lane >> 4;

  const float ald = al_d[(uint)node * 4u + head];
  float e0 = al_s[(uint)node * 4u + head] + ald;   // self loop
  e0 = e0 > 0.f ? e0 : NEG_SLOPE * e0;
  float m = __expf(e0);
  float denom = m;
  float acc = m * bf2f(h[((uint)node << 6) + lane]);

  const int beg = row_ptr[node];
  const int end = row_ptr[node + 1];
  int idx = beg;
  for (; idx + 8 <= end; idx += 8) {
    uint s[8]; float as[8]; float hv[8];
#pragma unroll
    for (int u = 0; u < 8; ++u) s[u] = (uint)col[idx + u];
#pragma unroll
    for (int u = 0; u < 8; ++u) as[u] = al_s[s[u] * 4u + head];
#pragma unroll
    for (int u = 0; u < 8; ++u) hv[u] = bf2f(h[(s[u] << 6) + lane]);
#pragma unroll
    for (int u = 0; u < 8; ++u) {
      float ee = as[u] + ald;
      ee = ee > 0.f ? ee : NEG_SLOPE * ee;
      float mm = __expf(ee);
      denom += mm;
      acc = fmaf(mm, hv[u], acc);
    }
  }
  for (; idx < end; ++idx) {
    uint s = (uint)col[idx];
    float ee = al_s[s * 4u + head] + ald;
    ee = ee > 0.f ? ee : NEG_SLOPE * ee;
    float mm = __expf(ee);
    denom += mm;
    acc = fmaf(mm, bf2f(h[(s << 6) + lane]), acc);
  }
  out_pre[((uint)node << 6) + lane] = acc / denom;
}

// ---------------- Kernel 8: BN statistics ----------------
__global__ __launch_bounds__(256) void stats_kernel(const float* __restrict__ out_pre,
                                                    float* __restrict__ sums) {
  const int c = threadIdx.x & 63;
  const int rg = threadIdx.x >> 6;
  float s = 0.f, s2 = 0.f;
  for (int r = blockIdx.x * 4 + rg; r < NN; r += gridDim.x * 4) {
    float v = out_pre[((uint)r << 6) + c];
    s += v;
    s2 = fmaf(v, v, s2);
  }
  __shared__ float lds[512];
  lds[threadIdx.x] = s;
  lds[256 + threadIdx.x] = s2;
  __syncthreads();
  if (threadIdx.x < 64) {
    float ts = lds[c] + lds[64 + c] + lds[128 + c] + lds[192 + c];
    float t2 = lds[256 + c] + lds[256 + 64 + c] + lds[256 + 128 + c] + lds[256 + 192 + c];
    atomicAdd(&sums[c], ts);
    atomicAdd(&sums[64 + c], t2);
  }
}

// ---------------- Kernel 9: BN + ELU + residual ----------------
__global__ __launch_bounds__(256) void final_kernel(
    const float* __restrict__ out_pre, const float* __restrict__ res,
    const float* __restrict__ sums, const float* __restrict__ gamma,
    const float* __restrict__ beta, float* __restrict__ out) {
  const int i = blockIdx.x * 256 + threadIdx.x;
  const int c = i & 63;
  const float inv_n = 1.0f / (float)NN;
  float mu = sums[c] * inv_n;
  float var = sums[64 + c] * inv_n - mu * mu;
  float rinv = rsqrtf(var + BN_EPS);
  float v = (out_pre[i] - mu) * rinv * gamma[c] + beta[c];
  v = v > 0.f ? v : (__expf(v) - 1.0f);
  out[i] = v + res[i];
}

extern "C" void kernel_launch(void* const* d_in, const int* in_sizes, int n_in,
                              void* d_out, int out_size, void* d_ws, size_t ws_size,
                              hipStream_t stream) {
  const float* x     = (const float*)d_in[0];
  const int*   ei    = (const int*)d_in[1];     // [2,E]: src = ei, dst = ei+E
  const float* W     = (const float*)d_in[2];
  const float* a_src = (const float*)d_in[3];
  const float* a_dst = (const float*)d_in[4];
  // d_in[5] = bias: cancels exactly through BatchNorm mean-subtraction -> unused
  const float* gamma = (const float*)d_in[6];
  const float* beta  = (const float*)d_in[7];
  const float* Wres  = (const float*)d_in[8];
  float* out = (float*)d_out;

  char* ws = (char*)d_ws;
  ushort* h        = (ushort*)ws; ws += (size_t)NN * HC * 2;   // bf16 h
  float* resb      = (float*)ws;  ws += (size_t)NN * HC * 4;
  float* out_pre   = (float*)ws;  ws += (size_t)NN * HC * 4;
  float* al_s      = (float*)ws;  ws += (size_t)NN * 4 * 4;
  float* al_d      = (float*)ws;  ws += (size_t)NN * 4 * 4;
  float* sums      = (float*)ws;  ws += 128 * 4;               // [0:64]=sum, [64:128]=sumsq
  int*   counts    = (int*)ws;    ws += (size_t)NN * 4;        // adjacent to sums: one zero pass
  int*   row_ptr   = (int*)ws;    ws += (size_t)(NN + 1) * 4;
  int*   blk_sums  = (int*)ws;    ws += 64 * 4;
  int*   histmat   = (int*)ws;    ws += (size_t)TOTH * 4;      // [bucket][block]
  uint*  pairs     = (uint*)ws;   ws += (size_t)EE * 4;
  int*   col       = (int*)ws;    ws += (size_t)EE * 4;

  zero_kernel<<<(NZERO / 4 + 255) / 256, 256, 0, stream>>>((int4*)sums);
  gemm_mfma_kernel<<<(NN + 63) / 64, 256, 0, stream>>>(x, W, Wres, a_src, a_dst,
                                                       h, resb, al_s, al_d);
  histB_kernel<<<NBLKS, 256, 0, stream>>>(ei + EE, counts, histmat);
  scan1_kernel<<<SCAN_NB, 256, 0, stream>>>(counts, row_ptr, blk_sums);
  scan3_kernel<<<(NN + 256) / 256, 256, 0, stream>>>(row_ptr, blk_sums);
  scanHB_kernel<<<NBKT, 256, 0, stream>>>(histmat, row_ptr);
  placeB_kernel<<<NBLKS, 256, 0, stream>>>(ei, ei + EE, histmat, pairs);
  bscatter_kernel<<<NBKT, 256, 0, stream>>>(pairs, row_ptr, col);
  node_kernel<<<NN / 4, 256, 0, stream>>>(h, al_s, al_d, row_ptr, col, out_pre);
  stats_kernel<<<256, 256, 0, stream>>>(out_pre, sums);
  final_kernel<<<NN * HC / 256, 256, 0, stream>>>(out_pre, resb, sums, gamma, beta, out);
}

// Round 11
// 136.760 us; speedup vs baseline: 3.6737x; 1.1268x over previous
//
#include <hip/hip_runtime.h>
#include <hip/hip_bf16.h>

#define NN 50000
#define EE 800000
#define IN_F 128
#define HC 64
#define NEG_SLOPE 0.2f
#define BN_EPS 1e-5f

#define NBKT 196          // buckets of 256 nodes: dst>>8 (max 49999>>8 = 195)
#define NBLKS 200         // sort blocks
#define EPB2 (EE / NBLKS) // 4000 edges per sort block
#define TOTH (NBKT * NBLKS)  // 39200

typedef __attribute__((ext_vector_type(8))) short short8;
typedef __attribute__((ext_vector_type(4))) float f32x4;

__device__ __forceinline__ ushort f2bf(float f) {
  uint u = __float_as_uint(f);
  uint r = u + 0x7FFF + ((u >> 16) & 1);   // RNE
  return (ushort)(r >> 16);
}
__device__ __forceinline__ float bf2f(ushort u) {
  return __uint_as_float(((uint)u) << 16);
}

// ---------------- Kernel 1: MFMA bf16 GEMM: h=x@W (bf16 out), res=x@Wres (f32), al_s, al_d --
__global__ __launch_bounds__(256) void gemm_mfma_kernel(
    const float* __restrict__ x, const float* __restrict__ W, const float* __restrict__ Wres,
    const float* __restrict__ a_src, const float* __restrict__ a_dst,
    ushort* __restrict__ h, float* __restrict__ res,
    float* __restrict__ al_s, float* __restrict__ al_d) {
  __shared__ ushort bs[128 * 128];   // [col][k] bf16, swizzled: byte ^= (col&7)<<4
  __shared__ ushort xs[64 * 128];    // [row][k] bf16, swizzled: byte ^= (row&7)<<4

  const int tid = threadIdx.x;
  const int r0 = blockIdx.x * 64;

  {
    const int c4 = (tid & 31) * 4;
    const int kb = (tid >> 5) * 16;
    const float* src0 = (c4 < HC) ? (W + c4) : (Wres + (c4 - HC));
    char* base = (char*)bs;
#pragma unroll
    for (int j = 0; j < 8; ++j) {
      int k0 = kb + j * 2;
      float4 fa = *(const float4*)(src0 + (size_t)k0 * HC);
      float4 fb = *(const float4*)(src0 + (size_t)(k0 + 1) * HC);
      uint p0 = (uint)f2bf(fa.x) | ((uint)f2bf(fb.x) << 16);
      uint p1 = (uint)f2bf(fa.y) | ((uint)f2bf(fb.y) << 16);
      uint p2 = (uint)f2bf(fa.z) | ((uint)f2bf(fb.z) << 16);
      uint p3 = (uint)f2bf(fa.w) | ((uint)f2bf(fb.w) << 16);
      *(uint*)(base + (((c4 + 0) * 256 + k0 * 2) ^ (((c4 + 0) & 7) << 4))) = p0;
      *(uint*)(base + (((c4 + 1) * 256 + k0 * 2) ^ (((c4 + 1) & 7) << 4))) = p1;
      *(uint*)(base + (((c4 + 2) * 256 + k0 * 2) ^ (((c4 + 2) & 7) << 4))) = p2;
      *(uint*)(base + (((c4 + 3) * 256 + k0 * 2) ^ (((c4 + 3) & 7) << 4))) = p3;
    }
  }
  {
    char* base = (char*)xs;
#pragma unroll
    for (int i = 0; i < 8; ++i) {
      int f4 = i * 256 + tid;
      int row = f4 >> 5;
      int kq = (f4 & 31) * 4;
      int gr = r0 + row;
      float4 v = make_float4(0.f, 0.f, 0.f, 0.f);
      if (gr < NN) v = *(const float4*)(x + (size_t)gr * IN_F + kq);
      uint lo = (uint)f2bf(v.x) | ((uint)f2bf(v.y) << 16);
      uint hi = (uint)f2bf(v.z) | ((uint)f2bf(v.w) << 16);
      uint off = (uint)((row * 256 + kq * 2) ^ ((row & 7) << 4));
      *(uint2*)(base + off) = make_uint2(lo, hi);
    }
  }
  __syncthreads();

  const int w = tid >> 6;
  const int l = tid & 63;
  const int lr = l & 15;
  const int lk = (l >> 4) * 8;

  f32x4 acc[8];
#pragma unroll
  for (int i = 0; i < 8; ++i) acc[i] = (f32x4){0.f, 0.f, 0.f, 0.f};

  const char* xb = (const char*)xs;
  const char* bb = (const char*)bs;
  const int arow = w * 16 + lr;
#pragma unroll
  for (int ks = 0; ks < 4; ++ks) {
    const int kbase = ks * 32 + lk;
    short8 af = *(const short8*)(xb + ((arow * 256 + kbase * 2) ^ ((arow & 7) << 4)));
#pragma unroll
    for (int ct = 0; ct < 8; ++ct) {
      const int c = ct * 16 + lr;
      short8 bfr = *(const short8*)(bb + ((c * 256 + kbase * 2) ^ ((c & 7) << 4)));
      acc[ct] = __builtin_amdgcn_mfma_f32_16x16x32_bf16(af, bfr, acc[ct], 0, 0, 0);
    }
  }

  const int rb = r0 + w * 16;
#pragma unroll
  for (int ct = 0; ct < 8; ++ct) {
#pragma unroll
    for (int r = 0; r < 4; ++r) {
      int gr = rb + (l >> 4) * 4 + r;
      if (gr < NN) {
        if (ct < 4) h[(size_t)gr * HC + ct * 16 + lr] = f2bf(acc[ct][r]);
        else        res[(size_t)gr * HC + (ct - 4) * 16 + lr] = acc[ct][r];
      }
    }
  }

  float myS[4] = {0.f, 0.f, 0.f, 0.f};
  float myD[4] = {0.f, 0.f, 0.f, 0.f};
#pragma unroll
  for (int ct = 0; ct < 4; ++ct) {
    float asv = a_src[ct * 16 + lr];
    float adv = a_dst[ct * 16 + lr];
#pragma unroll
    for (int r = 0; r < 4; ++r) {
      float ps = acc[ct][r] * asv;
      float pd = acc[ct][r] * adv;
      ps += __shfl_xor(ps, 1); ps += __shfl_xor(ps, 2); ps += __shfl_xor(ps, 4); ps += __shfl_xor(ps, 8);
      pd += __shfl_xor(pd, 1); pd += __shfl_xor(pd, 2); pd += __shfl_xor(pd, 4); pd += __shfl_xor(pd, 8);
      if (lr == ct) { myS[r] = ps; myD[r] = pd; }
    }
  }
  if (lr < 4) {
#pragma unroll
    for (int r = 0; r < 4; ++r) {
      int gr = rb + (l >> 4) * 4 + r;
      if (gr < NN) {
        al_s[gr * 4 + lr] = myS[r];
        al_d[gr * 4 + lr] = myD[r];
      }
    }
  }
}

// ---------------- Kernel 2: per-block bucket histogram (+ zero BN sums in block 0) -----
__global__ __launch_bounds__(256) void histB_kernel(const int* __restrict__ dst,
                                                    int* __restrict__ histmat,
                                                    float* __restrict__ sums) {
  __shared__ int lh[NBKT];
  const int tid = threadIdx.x;
  if (blockIdx.x == 0 && tid < 32)
    ((float4*)sums)[tid] = make_float4(0.f, 0.f, 0.f, 0.f);   // 128 floats
  for (int i = tid; i < NBKT; i += 256) lh[i] = 0;
  __syncthreads();
  const int ebase = blockIdx.x * EPB2;
  for (int off = tid; off < EPB2; off += 256)
    atomicAdd(&lh[dst[ebase + off] >> 8], 1);
  __syncthreads();
  for (int i = tid; i < NBKT; i += 256) histmat[i * NBLKS + blockIdx.x] = lh[i];
}

// ---------------- Kernel 3: per-bucket absolute bases (196 independent blocks) ---------
// Block b: prefix = cooperative sum of all earlier buckets' rows, then exclusive-scan
// own row -> histabs (absolute placement base per (bucket, sort-block)) + bucket_base.
__global__ __launch_bounds__(256) void scanB_kernel(const int* __restrict__ histmat,
                                                    int* __restrict__ histabs,
                                                    int* __restrict__ bucket_base) {
  const int b = blockIdx.x;
  const int t = threadIdx.x;
  const int lane = t & 63;
  const int wv = t >> 6;
  int part = 0;
  for (int i = t; i < b * NBLKS; i += 256) part += histmat[i];
#pragma unroll
  for (int off = 1; off < 64; off <<= 1) part += __shfl_xor(part, off);
  __shared__ int ws1[4];
  if (lane == 0) ws1[wv] = part;
  __syncthreads();
  const int prefix = ws1[0] + ws1[1] + ws1[2] + ws1[3];
  int v = (t < NBLKS) ? histmat[b * NBLKS + t] : 0;
  int incl = v;
#pragma unroll
  for (int off = 1; off < 64; off <<= 1) {
    int tt = __shfl_up(incl, off);
    if (lane >= off) incl += tt;
  }
  __shared__ int ws2[4];
  if (lane == 63) ws2[wv] = incl;
  __syncthreads();
  int woff = 0;
  for (int w = 0; w < wv; ++w) woff += ws2[w];
  if (t < NBLKS) histabs[b * NBLKS + t] = prefix + woff + incl - v;
  if (t == 0) bucket_base[b] = prefix;
  if (b == NBKT - 1 && t == 0) bucket_base[NBKT] = EE;
}

// ---------------- Kernel 4: place edges into bucket-sorted pairs ----------------
__global__ __launch_bounds__(256) void placeB_kernel(const int* __restrict__ src,
                                                     const int* __restrict__ dst,
                                                     const int* __restrict__ histabs,
                                                     uint* __restrict__ pairs) {
  __shared__ int cur[NBKT];
  const int tid = threadIdx.x;
  for (int i = tid; i < NBKT; i += 256) cur[i] = histabs[i * NBLKS + blockIdx.x];
  __syncthreads();
  const int ebase = blockIdx.x * EPB2;
  for (int off = tid; off < EPB2; off += 256) {
    const int e = ebase + off;
    const int d = dst[e];
    const uint val = ((uint)(d & 255) << 16) | (uint)src[e];
    int p = atomicAdd(&cur[d >> 8], 1);
    pairs[p] = val;
  }
}

// ---------------- Kernel 5: fine scatter; derives row_ptr locally (no global scan) -----
// Pass 1: count per-node degrees from bucket-resident pairs (L2-hot). Block-scan the
// 256 counters -> row_ptr for this bucket's nodes. Pass 2: scatter col via LDS cursors.
__global__ __launch_bounds__(256) void bscatter_kernel(const uint* __restrict__ pairs,
                                                       const int* __restrict__ bucket_base,
                                                       int* __restrict__ row_ptr,
                                                       int* __restrict__ col) {
  __shared__ int cnt[256];
  __shared__ int wsum[4];
  const int b = blockIdx.x;
  const int tid = threadIdx.x;
  cnt[tid] = 0;
  __syncthreads();
  const int lo = bucket_base[b];
  const int hi = bucket_base[b + 1];
  for (int i = lo + tid; i < hi; i += 256)
    atomicAdd(&cnt[(pairs[i] >> 16) & 255], 1);
  __syncthreads();
  const int lane = tid & 63;
  const int wv = tid >> 6;
  const int v = cnt[tid];
  int incl = v;
#pragma unroll
  for (int off = 1; off < 64; off <<= 1) {
    int t = __shfl_up(incl, off);
    if (lane >= off) incl += t;
  }
  if (lane == 63) wsum[wv] = incl;
  __syncthreads();
  int woff = 0;
  for (int w = 0; w < wv; ++w) woff += wsum[w];
  const int excl = lo + woff + incl - v;
  __syncthreads();
  cnt[tid] = excl;                     // reuse as cursor
  const int node = (b << 8) + tid;
  if (node < NN) row_ptr[node] = excl;
  if (b == NBKT - 1 && tid == 255) row_ptr[NN] = EE;
  __syncthreads();
  for (int i = lo + tid; i < hi; i += 256) {
    uint u = pairs[i];
    int d = (u >> 16) & 255;
    int p = atomicAdd(&cnt[d], 1);
    col[p] = (int)(u & 0xFFFFu);
  }
}

// ---------------- Kernel 6: per-node aggregate (wave per node, 32-bit addressing) ------
__global__ __launch_bounds__(256) void node_kernel(
    const ushort* __restrict__ h, const float* __restrict__ al_s, const float* __restrict__ al_d,
    const int* __restrict__ row_ptr, const int* __restrict__ col,
    float* __restrict__ out_pre) {
  const int node = blockIdx.x * 4 + (threadIdx.x >> 6);
  const uint lane = threadIdx.x & 63;
  const uint head = lane >> 4;

  const float ald = al_d[(uint)node * 4u + head];
  float e0 = al_s[(uint)node * 4u + head] + ald;   // self loop
  e0 = e0 > 0.f ? e0 : NEG_SLOPE * e0;
  float m = __expf(e0);
  float denom = m;
  float acc = m * bf2f(h[((uint)node << 6) + lane]);

  const int beg = row_ptr[node];
  const int end = row_ptr[node + 1];
  int idx = beg;
  for (; idx + 8 <= end; idx += 8) {
    uint s[8]; float as[8]; float hv[8];
#pragma unroll
    for (int u = 0; u < 8; ++u) s[u] = (uint)col[idx + u];
#pragma unroll
    for (int u = 0; u < 8; ++u) as[u] = al_s[s[u] * 4u + head];
#pragma unroll
    for (int u = 0; u < 8; ++u) hv[u] = bf2f(h[(s[u] << 6) + lane]);
#pragma unroll
    for (int u = 0; u < 8; ++u) {
      float ee = as[u] + ald;
      ee = ee > 0.f ? ee : NEG_SLOPE * ee;
      float mm = __expf(ee);
      denom += mm;
      acc = fmaf(mm, hv[u], acc);
    }
  }
  for (; idx < end; ++idx) {
    uint s = (uint)col[idx];
    float ee = al_s[s * 4u + head] + ald;
    ee = ee > 0.f ? ee : NEG_SLOPE * ee;
    float mm = __expf(ee);
    denom += mm;
    acc = fmaf(mm, bf2f(h[(s << 6) + lane]), acc);
  }
  out_pre[((uint)node << 6) + lane] = acc / denom;
}

// ---------------- Kernel 7: BN statistics ----------------
__global__ __launch_bounds__(256) void stats_kernel(const float* __restrict__ out_pre,
                                                    float* __restrict__ sums) {
  const int c = threadIdx.x & 63;
  const int rg = threadIdx.x >> 6;
  float s = 0.f, s2 = 0.f;
  for (int r = blockIdx.x * 4 + rg; r < NN; r += gridDim.x * 4) {
    float v = out_pre[((uint)r << 6) + c];
    s += v;
    s2 = fmaf(v, v, s2);
  }
  __shared__ float lds[512];
  lds[threadIdx.x] = s;
  lds[256 + threadIdx.x] = s2;
  __syncthreads();
  if (threadIdx.x < 64) {
    float ts = lds[c] + lds[64 + c] + lds[128 + c] + lds[192 + c];
    float t2 = lds[256 + c] + lds[256 + 64 + c] + lds[256 + 128 + c] + lds[256 + 192 + c];
    atomicAdd(&sums[c], ts);
    atomicAdd(&sums[64 + c], t2);
  }
}

// ---------------- Kernel 8: BN + ELU + residual ----------------
__global__ __launch_bounds__(256) void final_kernel(
    const float* __restrict__ out_pre, const float* __restrict__ res,
    const float* __restrict__ sums, const float* __restrict__ gamma,
    const float* __restrict__ beta, float* __restrict__ out) {
  const int i = blockIdx.x * 256 + threadIdx.x;
  const int c = i & 63;
  const float inv_n = 1.0f / (float)NN;
  float mu = sums[c] * inv_n;
  float var = sums[64 + c] * inv_n - mu * mu;
  float rinv = rsqrtf(var + BN_EPS);
  float v = (out_pre[i] - mu) * rinv * gamma[c] + beta[c];
  v = v > 0.f ? v : (__expf(v) - 1.0f);
  out[i] = v + res[i];
}

extern "C" void kernel_launch(void* const* d_in, const int* in_sizes, int n_in,
                              void* d_out, int out_size, void* d_ws, size_t ws_size,
                              hipStream_t stream) {
  const float* x     = (const float*)d_in[0];
  const int*   ei    = (const int*)d_in[1];     // [2,E]: src = ei, dst = ei+E
  const float* W     = (const float*)d_in[2];
  const float* a_src = (const float*)d_in[3];
  const float* a_dst = (const float*)d_in[4];
  // d_in[5] = bias: cancels exactly through BatchNorm mean-subtraction -> unused
  const float* gamma = (const float*)d_in[6];
  const float* beta  = (const float*)d_in[7];
  const float* Wres  = (const float*)d_in[8];
  float* out = (float*)d_out;

  char* ws = (char*)d_ws;
  ushort* h        = (ushort*)ws; ws += (size_t)NN * HC * 2;   // bf16 h
  float* resb      = (float*)ws;  ws += (size_t)NN * HC * 4;
  float* out_pre   = (float*)ws;  ws += (size_t)NN * HC * 4;
  float* al_s      = (float*)ws;  ws += (size_t)NN * 4 * 4;
  float* al_d      = (float*)ws;  ws += (size_t)NN * 4 * 4;
  float* sums      = (float*)ws;  ws += 128 * 4;               // [0:64]=sum, [64:128]=sumsq
  int*   row_ptr   = (int*)ws;    ws += (size_t)(NN + 1) * 4;
  int*   histmat   = (int*)ws;    ws += (size_t)TOTH * 4;      // [bucket][block]
  int*   histabs   = (int*)ws;    ws += (size_t)TOTH * 4;
  int*   bucket_base = (int*)ws;  ws += (NBKT + 1) * 4;
  uint*  pairs     = (uint*)ws;   ws += (size_t)EE * 4;
  int*   col       = (int*)ws;    ws += (size_t)EE * 4;

  gemm_mfma_kernel<<<(NN + 63) / 64, 256, 0, stream>>>(x, W, Wres, a_src, a_dst,
                                                       h, resb, al_s, al_d);
  histB_kernel<<<NBLKS, 256, 0, stream>>>(ei + EE, histmat, sums);
  scanB_kernel<<<NBKT, 256, 0, stream>>>(histmat, histabs, bucket_base);
  placeB_kernel<<<NBLKS, 256, 0, stream>>>(ei, ei + EE, histabs, pairs);
  bscatter_kernel<<<NBKT, 256, 0, stream>>>(pairs, bucket_base, row_ptr, col);
  node_kernel<<<NN / 4, 256, 0, stream>>>(h, al_s, al_d, row_ptr, col, out_pre);
  stats_kernel<<<256, 256, 0, stream>>>(out_pre, sums);
  final_kernel<<<NN * HC / 256, 256, 0, stream>>>(out_pre, resb, sums, gamma, beta, out);
}

// Round 12
// 130.776 us; speedup vs baseline: 3.8418x; 1.0458x over previous
//
#include <hip/hip_runtime.h>
#include <hip/hip_bf16.h>

#define NN 50000
#define EE 800000
#define IN_F 128
#define HC 64
#define NEG_SLOPE 0.2f
#define BN_EPS 1e-5f

#define NBKT 196          // buckets of 256 nodes: dst>>8 (max 49999>>8 = 195)
#define NBLKS 200         // sort blocks
#define EPB2 (EE / NBLKS) // 4000 edges per sort block
#define TOTH (NBKT * NBLKS)  // 39200

typedef __attribute__((ext_vector_type(8))) short short8;
typedef __attribute__((ext_vector_type(4))) float f32x4;

__device__ __forceinline__ ushort f2bf(float f) {
  uint u = __float_as_uint(f);
  uint r = u + 0x7FFF + ((u >> 16) & 1);   // RNE
  return (ushort)(r >> 16);
}
__device__ __forceinline__ float bf2f(ushort u) {
  return __uint_as_float(((uint)u) << 16);
}

// ---------------- Kernel 1: MFMA bf16 GEMM: h=x@W (bf16), res=x@Wres (bf16), al_s, al_d --
__global__ __launch_bounds__(256) void gemm_mfma_kernel(
    const float* __restrict__ x, const float* __restrict__ W, const float* __restrict__ Wres,
    const float* __restrict__ a_src, const float* __restrict__ a_dst,
    ushort* __restrict__ h, ushort* __restrict__ res,
    float* __restrict__ al_s, float* __restrict__ al_d) {
  __shared__ ushort bs[128 * 128];   // [col][k] bf16, swizzled: byte ^= (col&7)<<4
  __shared__ ushort xs[64 * 128];    // [row][k] bf16, swizzled: byte ^= (row&7)<<4

  const int tid = threadIdx.x;
  const int r0 = blockIdx.x * 64;

  {
    const int c4 = (tid & 31) * 4;
    const int kb = (tid >> 5) * 16;
    const float* src0 = (c4 < HC) ? (W + c4) : (Wres + (c4 - HC));
    char* base = (char*)bs;
#pragma unroll
    for (int j = 0; j < 8; ++j) {
      int k0 = kb + j * 2;
      float4 fa = *(const float4*)(src0 + (size_t)k0 * HC);
      float4 fb = *(const float4*)(src0 + (size_t)(k0 + 1) * HC);
      uint p0 = (uint)f2bf(fa.x) | ((uint)f2bf(fb.x) << 16);
      uint p1 = (uint)f2bf(fa.y) | ((uint)f2bf(fb.y) << 16);
      uint p2 = (uint)f2bf(fa.z) | ((uint)f2bf(fb.z) << 16);
      uint p3 = (uint)f2bf(fa.w) | ((uint)f2bf(fb.w) << 16);
      *(uint*)(base + (((c4 + 0) * 256 + k0 * 2) ^ (((c4 + 0) & 7) << 4))) = p0;
      *(uint*)(base + (((c4 + 1) * 256 + k0 * 2) ^ (((c4 + 1) & 7) << 4))) = p1;
      *(uint*)(base + (((c4 + 2) * 256 + k0 * 2) ^ (((c4 + 2) & 7) << 4))) = p2;
      *(uint*)(base + (((c4 + 3) * 256 + k0 * 2) ^ (((c4 + 3) & 7) << 4))) = p3;
    }
  }
  {
    char* base = (char*)xs;
#pragma unroll
    for (int i = 0; i < 8; ++i) {
      int f4 = i * 256 + tid;
      int row = f4 >> 5;
      int kq = (f4 & 31) * 4;
      int gr = r0 + row;
      float4 v = make_float4(0.f, 0.f, 0.f, 0.f);
      if (gr < NN) v = *(const float4*)(x + (size_t)gr * IN_F + kq);
      uint lo = (uint)f2bf(v.x) | ((uint)f2bf(v.y) << 16);
      uint hi = (uint)f2bf(v.z) | ((uint)f2bf(v.w) << 16);
      uint off = (uint)((row * 256 + kq * 2) ^ ((row & 7) << 4));
      *(uint2*)(base + off) = make_uint2(lo, hi);
    }
  }
  __syncthreads();

  const int w = tid >> 6;
  const int l = tid & 63;
  const int lr = l & 15;
  const int lk = (l >> 4) * 8;

  f32x4 acc[8];
#pragma unroll
  for (int i = 0; i < 8; ++i) acc[i] = (f32x4){0.f, 0.f, 0.f, 0.f};

  const char* xb = (const char*)xs;
  const char* bb = (const char*)bs;
  const int arow = w * 16 + lr;
#pragma unroll
  for (int ks = 0; ks < 4; ++ks) {
    const int kbase = ks * 32 + lk;
    short8 af = *(const short8*)(xb + ((arow * 256 + kbase * 2) ^ ((arow & 7) << 4)));
#pragma unroll
    for (int ct = 0; ct < 8; ++ct) {
      const int c = ct * 16 + lr;
      short8 bfr = *(const short8*)(bb + ((c * 256 + kbase * 2) ^ ((c & 7) << 4)));
      acc[ct] = __builtin_amdgcn_mfma_f32_16x16x32_bf16(af, bfr, acc[ct], 0, 0, 0);
    }
  }

  const int rb = r0 + w * 16;
#pragma unroll
  for (int ct = 0; ct < 8; ++ct) {
#pragma unroll
    for (int r = 0; r < 4; ++r) {
      int gr = rb + (l >> 4) * 4 + r;
      if (gr < NN) {
        if (ct < 4) h[(size_t)gr * HC + ct * 16 + lr] = f2bf(acc[ct][r]);
        else        res[(size_t)gr * HC + (ct - 4) * 16 + lr] = f2bf(acc[ct][r]);
      }
    }
  }

  float myS[4] = {0.f, 0.f, 0.f, 0.f};
  float myD[4] = {0.f, 0.f, 0.f, 0.f};
#pragma unroll
  for (int ct = 0; ct < 4; ++ct) {
    float asv = a_src[ct * 16 + lr];
    float adv = a_dst[ct * 16 + lr];
#pragma unroll
    for (int r = 0; r < 4; ++r) {
      float ps = acc[ct][r] * asv;
      float pd = acc[ct][r] * adv;
      ps += __shfl_xor(ps, 1); ps += __shfl_xor(ps, 2); ps += __shfl_xor(ps, 4); ps += __shfl_xor(ps, 8);
      pd += __shfl_xor(pd, 1); pd += __shfl_xor(pd, 2); pd += __shfl_xor(pd, 4); pd += __shfl_xor(pd, 8);
      if (lr == ct) { myS[r] = ps; myD[r] = pd; }
    }
  }
  if (lr < 4) {
#pragma unroll
    for (int r = 0; r < 4; ++r) {
      int gr = rb + (l >> 4) * 4 + r;
      if (gr < NN) {
        al_s[gr * 4 + lr] = myS[r];
        al_d[gr * 4 + lr] = myD[r];
      }
    }
  }
}

// ---------------- Kernel 2: per-block bucket histogram, int4-vectorized ----------------
__global__ __launch_bounds__(256) void histB_kernel(const int* __restrict__ dst,
                                                    int* __restrict__ histmat,
                                                    float* __restrict__ sums) {
  __shared__ int lh[NBKT];
  const int tid = threadIdx.x;
  if (blockIdx.x == 0 && tid < 32)
    ((float4*)sums)[tid] = make_float4(0.f, 0.f, 0.f, 0.f);   // 128 floats
  for (int i = tid; i < NBKT; i += 256) lh[i] = 0;
  __syncthreads();
  const int4* d4 = (const int4*)(dst + blockIdx.x * EPB2);
  for (int p = tid; p < EPB2 / 4; p += 256) {
    int4 d = d4[p];
    atomicAdd(&lh[d.x >> 8], 1);
    atomicAdd(&lh[d.y >> 8], 1);
    atomicAdd(&lh[d.z >> 8], 1);
    atomicAdd(&lh[d.w >> 8], 1);
  }
  __syncthreads();
  for (int i = tid; i < NBKT; i += 256) histmat[i * NBLKS + blockIdx.x] = lh[i];
}

// ---------------- Kernel 3: per-bucket absolute bases (196 independent blocks) ---------
__global__ __launch_bounds__(256) void scanB_kernel(const int* __restrict__ histmat,
                                                    int* __restrict__ histabs,
                                                    int* __restrict__ bucket_base) {
  const int b = blockIdx.x;
  const int t = threadIdx.x;
  const int lane = t & 63;
  const int wv = t >> 6;
  int part = 0;
  for (int i = t; i < b * NBLKS; i += 256) part += histmat[i];
#pragma unroll
  for (int off = 1; off < 64; off <<= 1) part += __shfl_xor(part, off);
  __shared__ int ws1[4];
  if (lane == 0) ws1[wv] = part;
  __syncthreads();
  const int prefix = ws1[0] + ws1[1] + ws1[2] + ws1[3];
  int v = (t < NBLKS) ? histmat[b * NBLKS + t] : 0;
  int incl = v;
#pragma unroll
  for (int off = 1; off < 64; off <<= 1) {
    int tt = __shfl_up(incl, off);
    if (lane >= off) incl += tt;
  }
  __shared__ int ws2[4];
  if (lane == 63) ws2[wv] = incl;
  __syncthreads();
  int woff = 0;
  for (int w = 0; w < wv; ++w) woff += ws2[w];
  if (t < NBLKS) histabs[b * NBLKS + t] = prefix + woff + incl - v;
  if (t == 0) bucket_base[b] = prefix;
  if (b == NBKT - 1 && t == 0) bucket_base[NBKT] = EE;
}

// ---------------- Kernel 4: place edges into bucket-sorted pairs (int4 loads) ----------
__global__ __launch_bounds__(256) void placeB_kernel(const int* __restrict__ src,
                                                     const int* __restrict__ dst,
                                                     const int* __restrict__ histabs,
                                                     uint* __restrict__ pairs) {
  __shared__ int cur[NBKT];
  const int tid = threadIdx.x;
  for (int i = tid; i < NBKT; i += 256) cur[i] = histabs[i * NBLKS + blockIdx.x];
  __syncthreads();
  const int4* s4 = (const int4*)(src + blockIdx.x * EPB2);
  const int4* d4 = (const int4*)(dst + blockIdx.x * EPB2);
  for (int p = tid; p < EPB2 / 4; p += 256) {
    int4 d = d4[p];
    int4 s = s4[p];
    int q;
    q = atomicAdd(&cur[d.x >> 8], 1); pairs[q] = ((uint)(d.x & 255) << 16) | (uint)s.x;
    q = atomicAdd(&cur[d.y >> 8], 1); pairs[q] = ((uint)(d.y & 255) << 16) | (uint)s.y;
    q = atomicAdd(&cur[d.z >> 8], 1); pairs[q] = ((uint)(d.z & 255) << 16) | (uint)s.z;
    q = atomicAdd(&cur[d.w >> 8], 1); pairs[q] = ((uint)(d.w & 255) << 16) | (uint)s.w;
  }
}

// ---------------- Kernel 5: fine scatter; derives row_ptr locally ----------------
__global__ __launch_bounds__(256) void bscatter_kernel(const uint* __restrict__ pairs,
                                                       const int* __restrict__ bucket_base,
                                                       int* __restrict__ row_ptr,
                                                       int* __restrict__ col) {
  __shared__ int cnt[256];
  __shared__ int wsum[4];
  const int b = blockIdx.x;
  const int tid = threadIdx.x;
  cnt[tid] = 0;
  __syncthreads();
  const int lo = bucket_base[b];
  const int hi = bucket_base[b + 1];
  for (int i = lo + tid; i < hi; i += 256)
    atomicAdd(&cnt[(pairs[i] >> 16) & 255], 1);
  __syncthreads();
  const int lane = tid & 63;
  const int wv = tid >> 6;
  const int v = cnt[tid];
  int incl = v;
#pragma unroll
  for (int off = 1; off < 64; off <<= 1) {
    int t = __shfl_up(incl, off);
    if (lane >= off) incl += t;
  }
  if (lane == 63) wsum[wv] = incl;
  __syncthreads();
  int woff = 0;
  for (int w = 0; w < wv; ++w) woff += wsum[w];
  const int excl = lo + woff + incl - v;
  __syncthreads();
  cnt[tid] = excl;                     // reuse as cursor
  const int node = (b << 8) + tid;
  if (node < NN) row_ptr[node] = excl;
  if (b == NBKT - 1 && tid == 255) row_ptr[NN] = EE;
  __syncthreads();
  for (int i = lo + tid; i < hi; i += 256) {
    uint u = pairs[i];
    int d = (u >> 16) & 255;
    int p = atomicAdd(&cnt[d], 1);
    col[p] = (int)(u & 0xFFFFu);
  }
}

// ---------------- Kernel 6: per-node aggregate (predicated batch, no serial tail) ------
__global__ __launch_bounds__(256) void node_kernel(
    const ushort* __restrict__ h, const float* __restrict__ al_s, const float* __restrict__ al_d,
    const int* __restrict__ row_ptr, const int* __restrict__ col,
    ushort* __restrict__ out_pre) {
  const int node = blockIdx.x * 4 + (threadIdx.x >> 6);
  const uint lane = threadIdx.x & 63;
  const uint head = lane >> 4;

  const float ald = al_d[(uint)node * 4u + head];
  float e0 = al_s[(uint)node * 4u + head] + ald;   // self loop
  e0 = e0 > 0.f ? e0 : NEG_SLOPE * e0;
  float m = __expf(e0);
  float denom = m;
  float acc = m * bf2f(h[((uint)node << 6) + lane]);

  const int beg = row_ptr[node];
  const int end = row_ptr[node + 1];
  for (int idx = beg; idx < end; idx += 8) {
    uint s[8]; float as[8]; float hv[8];
#pragma unroll
    for (int u = 0; u < 8; ++u) {
      int j = idx + u;
      s[u] = (uint)col[j < end ? j : beg];   // clamp: beg always valid here
    }
#pragma unroll
    for (int u = 0; u < 8; ++u) as[u] = al_s[s[u] * 4u + head];
#pragma unroll
    for (int u = 0; u < 8; ++u) hv[u] = bf2f(h[(s[u] << 6) + lane]);
#pragma unroll
    for (int u = 0; u < 8; ++u) {
      float ee = as[u] + ald;
      ee = ee > 0.f ? ee : NEG_SLOPE * ee;
      float mm = (idx + u < end) ? __expf(ee) : 0.f;   // predicate kills tail lanes
      denom += mm;
      acc = fmaf(mm, hv[u], acc);
    }
  }
  out_pre[((uint)node << 6) + lane] = f2bf(acc / denom);
}

// ---------------- Kernel 7: BN statistics (bf16 in, uint-paired loads) ----------------
__global__ __launch_bounds__(256) void stats_kernel(const uint* __restrict__ out_pre_u,
                                                    float* __restrict__ sums) {
  const int tid = threadIdx.x;
  const int c2 = tid & 31;             // channel pair: channels 2*c2, 2*c2+1
  const int rg = tid >> 5;             // 8 row groups
  float s0 = 0.f, s1 = 0.f, q0 = 0.f, q1 = 0.f;
  for (int r = blockIdx.x * 8 + rg; r < NN; r += gridDim.x * 8) {
    uint u = out_pre_u[((uint)r << 5) + c2];
    float v0 = bf2f((ushort)(u & 0xFFFFu));
    float v1 = bf2f((ushort)(u >> 16));
    s0 += v0; s1 += v1;
    q0 = fmaf(v0, v0, q0); q1 = fmaf(v1, v1, q1);
  }
  __shared__ float l0[256], l1[256], l2[256], l3[256];
  l0[tid] = s0; l1[tid] = s1; l2[tid] = q0; l3[tid] = q1;
  __syncthreads();
  if (tid < 32) {
    float a0 = 0.f, a1 = 0.f, a2 = 0.f, a3 = 0.f;
#pragma unroll
    for (int g = 0; g < 8; ++g) {
      a0 += l0[g * 32 + tid]; a1 += l1[g * 32 + tid];
      a2 += l2[g * 32 + tid]; a3 += l3[g * 32 + tid];
    }
    atomicAdd(&sums[tid * 2], a0);
    atomicAdd(&sums[tid * 2 + 1], a1);
    atomicAdd(&sums[64 + tid * 2], a2);
    atomicAdd(&sums[64 + tid * 2 + 1], a3);
  }
}

// ---------------- Kernel 8: BN + ELU + residual (4 elems/thread) ----------------
__global__ __launch_bounds__(256) void final_kernel(
    const uint* __restrict__ out_pre_u, const uint* __restrict__ res_u,
    const float* __restrict__ sums, const float* __restrict__ gamma,
    const float* __restrict__ beta, float* __restrict__ out) {
  const int i = blockIdx.x * 256 + threadIdx.x;     // quad index; 3125*256 == NN*HC/4
  const int c4 = (i & 15) * 4;
  const float inv_n = 1.0f / (float)NN;
  uint2 op = *(const uint2*)&out_pre_u[(size_t)i * 2];
  uint2 rs = *(const uint2*)&res_u[(size_t)i * 2];
  float4 g4 = *(const float4*)&gamma[c4];
  float4 b4 = *(const float4*)&beta[c4];
  float pv[4] = { bf2f((ushort)(op.x & 0xFFFFu)), bf2f((ushort)(op.x >> 16)),
                  bf2f((ushort)(op.y & 0xFFFFu)), bf2f((ushort)(op.y >> 16)) };
  float rv[4] = { bf2f((ushort)(rs.x & 0xFFFFu)), bf2f((ushort)(rs.x >> 16)),
                  bf2f((ushort)(rs.y & 0xFFFFu)), bf2f((ushort)(rs.y >> 16)) };
  float gg[4] = { g4.x, g4.y, g4.z, g4.w };
  float bb[4] = { b4.x, b4.y, b4.z, b4.w };
  float4 o;
  float* po = &o.x;
#pragma unroll
  for (int k = 0; k < 4; ++k) {
    int c = c4 + k;
    float mu = sums[c] * inv_n;
    float var = sums[64 + c] * inv_n - mu * mu;
    float rinv = rsqrtf(var + BN_EPS);
    float v = (pv[k] - mu) * rinv * gg[k] + bb[k];
    v = v > 0.f ? v : (__expf(v) - 1.0f);
    po[k] = v + rv[k];
  }
  *(float4*)&out[(size_t)i * 4] = o;
}

extern "C" void kernel_launch(void* const* d_in, const int* in_sizes, int n_in,
                              void* d_out, int out_size, void* d_ws, size_t ws_size,
                              hipStream_t stream) {
  const float* x     = (const float*)d_in[0];
  const int*   ei    = (const int*)d_in[1];     // [2,E]: src = ei, dst = ei+E
  const float* W     = (const float*)d_in[2];
  const float* a_src = (const float*)d_in[3];
  const float* a_dst = (const float*)d_in[4];
  // d_in[5] = bias: cancels exactly through BatchNorm mean-subtraction -> unused
  const float* gamma = (const float*)d_in[6];
  const float* beta  = (const float*)d_in[7];
  const float* Wres  = (const float*)d_in[8];
  float* out = (float*)d_out;

  char* ws = (char*)d_ws;
  ushort* h        = (ushort*)ws; ws += (size_t)NN * HC * 2;   // bf16 h
  ushort* resb     = (ushort*)ws; ws += (size_t)NN * HC * 2;   // bf16 res
  ushort* out_pre  = (ushort*)ws; ws += (size_t)NN * HC * 2;   // bf16 out_pre
  float* al_s      = (float*)ws;  ws += (size_t)NN * 4 * 4;
  float* al_d      = (float*)ws;  ws += (size_t)NN * 4 * 4;
  float* sums      = (float*)ws;  ws += 128 * 4;               // [0:64]=sum, [64:128]=sumsq
  int*   row_ptr   = (int*)ws;    ws += (size_t)(NN + 1) * 4;
  int*   histmat   = (int*)ws;    ws += (size_t)TOTH * 4;      // [bucket][block]
  int*   histabs   = (int*)ws;    ws += (size_t)TOTH * 4;
  int*   bucket_base = (int*)ws;  ws += (NBKT + 1) * 4;
  uint*  pairs     = (uint*)ws;   ws += (size_t)EE * 4;
  int*   col       = (int*)ws;    ws += (size_t)EE * 4;

  gemm_mfma_kernel<<<(NN + 63) / 64, 256, 0, stream>>>(x, W, Wres, a_src, a_dst,
                                                       h, resb, al_s, al_d);
  histB_kernel<<<NBLKS, 256, 0, stream>>>(ei + EE, histmat, sums);
  scanB_kernel<<<NBKT, 256, 0, stream>>>(histmat, histabs, bucket_base);
  placeB_kernel<<<NBLKS, 256, 0, stream>>>(ei, ei + EE, histabs, pairs);
  bscatter_kernel<<<NBKT, 256, 0, stream>>>(pairs, bucket_base, row_ptr, col);
  node_kernel<<<NN / 4, 256, 0, stream>>>(h, al_s, al_d, row_ptr, col, out_pre);
  stats_kernel<<<256, 256, 0, stream>>>((const uint*)out_pre, sums);
  final_kernel<<<NN * HC / 1024, 256, 0, stream>>>((const uint*)out_pre, (const uint*)resb,
                                                   sums, gamma, beta, out);
}